// Round 1
// baseline (612.040 us; speedup 1.0000x reference)
//
#include <hip/hip_runtime.h>
#include <hip/hip_bf16.h>
#include <math.h>

#define B_ 16
#define L_ 32768
#define H_ 64
#define N_ 16
#define DM_ 32
#define T_ 128
#define C_ 256   /* L_/T_ */

// gelu matching jax.nn.gelu(approximate=True):
// 0.5*x*(1+tanh(sqrt(2/pi)*(x+0.044715 x^3)))
__device__ __forceinline__ float fast_gelu(float v) {
    float z = fmaf(0.044715f * v, v * v, v) * 0.7978845608028654f;
#if __has_builtin(__builtin_amdgcn_exp2f) && __has_builtin(__builtin_amdgcn_rcpf)
    // tanh(z) = 1 - 2/(1+exp(2z));  exp(2z) = 2^(z*2*log2(e))
    float e = __builtin_amdgcn_exp2f(z * 2.8853900817779268f);
    float t = 1.0f - 2.0f * __builtin_amdgcn_rcpf(e + 1.0f);
#else
    float t = tanhf(z);
#endif
    return 0.5f * v * (1.0f + t);
}

// ---------------- kernel 0a: cond MLP + FiLM params ----------------
__global__ void cond_film_kernel(const float* __restrict__ cp,
    const float* __restrict__ W0, const float* __restrict__ b0,
    const float* __restrict__ W1, const float* __restrict__ b1,
    const float* __restrict__ W2, const float* __restrict__ b2,
    const float* __restrict__ Wf, const float* __restrict__ bf,
    float* __restrict__ film) {
    __shared__ float ca[B_][DM_];
    __shared__ float cb[B_][DM_];
    int tid = threadIdx.x;            // 512 threads = 16 b * 32 j
    int b = tid >> 5, j = tid & 31;
    float acc = fmaf(cp[b*2+0], W0[j], fmaf(cp[b*2+1], W0[DM_+j], b0[j]));
    ca[b][j] = fast_gelu(acc);
    __syncthreads();
    acc = b1[j];
    #pragma unroll
    for (int i = 0; i < DM_; ++i) acc = fmaf(ca[b][i], W1[i*DM_+j], acc);
    cb[b][j] = fast_gelu(acc);
    __syncthreads();
    acc = b2[j];
    #pragma unroll
    for (int i = 0; i < DM_; ++i) acc = fmaf(cb[b][i], W2[i*DM_+j], acc);
    float c2 = fast_gelu(acc);
    __syncthreads();
    ca[b][j] = c2;
    __syncthreads();
    #pragma unroll
    for (int t = 0; t < 4; ++t) {
        int k = j + DM_*t;            // 0..127
        float a = bf[k];
        #pragma unroll
        for (int i = 0; i < DM_; ++i) a = fmaf(ca[b][i], Wf[i*2*H_+k], a);
        film[b*2*H_ + k] = a;         // [0:64)=gamma, [64:128)=beta
    }
}

// ---------------- kernel 0b: SSM coefficients ----------------
// coef layout: coef[(n*6+f)*H_ + h], f = {wr, wi, wTr, wTi, 2cr, 2ci}
__global__ void coef_kernel(const float* __restrict__ log_dt,
    const float* __restrict__ A_re, const float* __restrict__ A_im,
    const float* __restrict__ C_re, const float* __restrict__ C_im,
    float* __restrict__ coef) {
    int g = blockIdx.x * blockDim.x + threadIdx.x;   // 1024
    if (g >= H_*N_) return;
    int h = g >> 4, n = g & 15;
    float dt = expf(log_dt[h]);
    float Ar = A_re[h*N_+n], Ai = A_im[h*N_+n];
    float ar = dt*Ar, ai = dt*Ai;
    float er = expf(ar);
    float wr = er * cosf(ai), wi = er * sinf(ai);
    float eT = expf((float)T_ * ar);
    float aT = (float)T_ * ai;
    float wTr = eT * cosf(aT), wTi = eT * sinf(aT);
    // (w - 1)/A   (A is the undiscretized A)
    float d  = Ar*Ar + Ai*Ai;
    float nr = wr - 1.0f, ni = wi;
    float qr = (nr*Ar + ni*Ai) / d;
    float qi = (ni*Ar - nr*Ai) / d;
    float Cr = C_re[h*N_+n], Ci = C_im[h*N_+n];
    float cr = 2.0f * (Cr*qr - Ci*qi);   // fold the 2*Re() factor in
    float ci = 2.0f * (Cr*qi + Ci*qr);
    coef[(n*6+0)*H_+h] = wr;
    coef[(n*6+1)*H_+h] = wi;
    coef[(n*6+2)*H_+h] = wTr;
    coef[(n*6+3)*H_+h] = wTi;
    coef[(n*6+4)*H_+h] = cr;
    coef[(n*6+5)*H_+h] = ci;
}

// ---------------- phase 2: cross-chunk prefix combine ----------------
// states layout: states[(((b*C_ + c)*N_ + n)*H_ + h)*2 + {0,1}]
__global__ void chunk_scan_kernel(float* __restrict__ states,
                                  const float* __restrict__ coef) {
    int t = blockIdx.x * blockDim.x + threadIdx.x;   // 16384 = B*N*H
    int h = t & 63, n = (t >> 6) & 15, b = t >> 10;
    float wTr = coef[(n*6+2)*H_+h], wTi = coef[(n*6+3)*H_+h];
    float car = 0.f, cai = 0.f;    // state at START of chunk c
    for (int c = 0; c < C_; ++c) {
        size_t idx = (((size_t)(b*C_ + c)*N_ + n)*H_ + h)*2;
        float lr = states[idx], li = states[idx+1];
        states[idx]   = car;
        states[idx+1] = cai;
        float nr2 = fmaf(wTr, car, fmaf(-wTi, cai, lr));
        float ni2 = fmaf(wTr, cai, fmaf( wTi, car, li));
        car = nr2; cai = ni2;
    }
}

// ---------------- phases 1 & 3: the chunk scan ----------------
// PHASE 1: zero-init, write end-of-chunk local states.
// PHASE 3: init from prefix states, write final output (FiLM+gelu+gate fused).
template<int PHASE>
__global__ __launch_bounds__(64, 2)
void scan_kernel(const float* __restrict__ x,
                 const float* __restrict__ W_lin, const float* __restrict__ b_lin,
                 const float* __restrict__ coef, float* __restrict__ states,
                 const float* __restrict__ D, const float* __restrict__ film,
                 float* __restrict__ out) {
    __shared__ float sx[32*64];            // one 32-row x subtile (8 KB)
    const int lane = threadIdx.x;          // = h
    const int bid  = blockIdx.x;
    const int b = bid / C_;
    const int c = bid % C_;
    const int l0 = c * T_;

    // W column register-stationary: wcol[k] = W_lin[k][lane]
    float wcol[64];
    #pragma unroll
    for (int k = 0; k < 64; ++k) wcol[k] = W_lin[k*H_ + lane];
    const float blin = b_lin[lane];

    float wr[N_], wi[N_], sr[N_], si[N_];
    float cr[N_], ci[N_];
    float g_ = 0.f, be_ = 0.f, Dh = 0.f;
    #pragma unroll
    for (int n = 0; n < N_; ++n) {
        wr[n] = coef[(n*6+0)*H_ + lane];
        wi[n] = coef[(n*6+1)*H_ + lane];
    }
    if (PHASE == 1) {
        #pragma unroll
        for (int n = 0; n < N_; ++n) { sr[n] = 0.f; si[n] = 0.f; }
    } else {
        #pragma unroll
        for (int n = 0; n < N_; ++n) {
            cr[n] = coef[(n*6+4)*H_ + lane];
            ci[n] = coef[(n*6+5)*H_ + lane];
            size_t idx = (((size_t)(b*C_ + c)*N_ + n)*H_ + lane)*2;
            sr[n] = states[idx]; si[n] = states[idx+1];
        }
        g_  = film[b*2*H_ + lane];
        be_ = film[b*2*H_ + H_ + lane];
        Dh  = D[lane];
    }

    const float4* xg = (const float4*)(x + ((size_t)b*L_ + l0)*H_);
    float4* sx4 = (float4*)sx;
    float* outp = (PHASE == 3) ? (out + ((size_t)b*L_ + l0)*H_) : nullptr;

    for (int s = 0; s < T_/32; ++s) {
        // stage 32 rows of x (contiguous 8 KB) into LDS, coalesced float4
        #pragma unroll
        for (int i = 0; i < 8; ++i)
            sx4[i*64 + lane] = xg[(size_t)s*512 + i*64 + lane];
        __syncthreads();
        for (int l = 0; l < 32; ++l) {
            // h[l][lane] = gelu(b_lin + sum_k x[l][k]*W[k][lane])
            // x row broadcast from LDS (same-address ds_read_b128), W in regs
            const float4* xr = (const float4*)(sx + l*64);
            float a0 = blin, a1 = 0.f, a2 = 0.f, a3 = 0.f;
            #pragma unroll
            for (int k4 = 0; k4 < 16; ++k4) {
                float4 v = xr[k4];
                a0 = fmaf(v.x, wcol[k4*4+0], a0);
                a1 = fmaf(v.y, wcol[k4*4+1], a1);
                a2 = fmaf(v.z, wcol[k4*4+2], a2);
                a3 = fmaf(v.w, wcol[k4*4+3], a3);
            }
            float u = fast_gelu((a0 + a1) + (a2 + a3));
            float y0 = 0.f, y1 = 0.f;
            #pragma unroll
            for (int n = 0; n < N_; ++n) {
                float nr = fmaf(wr[n], sr[n], fmaf(-wi[n], si[n], u));
                float ni = fmaf(wr[n], si[n], wi[n]*sr[n]);
                sr[n] = nr; si[n] = ni;
                if (PHASE == 3) {
                    y0 = fmaf(cr[n], nr, y0);
                    y1 = fmaf(ci[n], ni, y1);
                }
            }
            if (PHASE == 3) {
                float y  = fmaf(Dh, u, y0 - y1);     // conv + D*u
                float v2 = fmaf(y, g_, be_);          // FiLM
                float yg = fast_gelu(v2);
                float xv = sx[l*64 + lane];
                outp[(s*32 + l)*H_ + lane] = xv * yg; // side-chain gate
            }
        }
        __syncthreads();
    }
    if (PHASE == 1) {
        #pragma unroll
        for (int n = 0; n < N_; ++n) {
            size_t idx = (((size_t)(b*C_ + c)*N_ + n)*H_ + lane)*2;
            states[idx]   = sr[n];
            states[idx+1] = si[n];
        }
    }
}

extern "C" void kernel_launch(void* const* d_in, const int* in_sizes, int n_in,
                              void* d_out, int out_size, void* d_ws, size_t ws_size,
                              hipStream_t stream) {
    const float* x     = (const float*)d_in[0];
    const float* cp    = (const float*)d_in[1];
    const float* W0    = (const float*)d_in[2];
    const float* b0    = (const float*)d_in[3];
    const float* W1    = (const float*)d_in[4];
    const float* b1    = (const float*)d_in[5];
    const float* W2    = (const float*)d_in[6];
    const float* b2    = (const float*)d_in[7];
    const float* W_lin = (const float*)d_in[8];
    const float* b_lin = (const float*)d_in[9];
    const float* log_dt= (const float*)d_in[10];
    const float* A_re  = (const float*)d_in[11];
    const float* A_im  = (const float*)d_in[12];
    const float* C_re  = (const float*)d_in[13];
    const float* C_im  = (const float*)d_in[14];
    const float* D     = (const float*)d_in[15];
    const float* W_f   = (const float*)d_in[16];
    const float* b_f   = (const float*)d_in[17];
    float* out = (float*)d_out;

    float* film   = (float*)d_ws;                  // B*2H       = 2048 floats
    float* coef   = film + B_*2*H_;                // 6*H*N      = 6144 floats
    float* states = coef + 6*H_*N_;                // B*C*N*H*2  = 8.4M floats

    cond_film_kernel<<<1, 512, 0, stream>>>(cp, W0, b0, W1, b1, W2, b2,
                                            W_f, b_f, film);
    coef_kernel<<<4, 256, 0, stream>>>(log_dt, A_re, A_im, C_re, C_im, coef);
    scan_kernel<1><<<B_*C_, 64, 0, stream>>>(x, W_lin, b_lin, coef, states,
                                             nullptr, nullptr, nullptr);
    chunk_scan_kernel<<<(B_*N_*H_)/256, 256, 0, stream>>>(states, coef);
    scan_kernel<3><<<B_*C_, 64, 0, stream>>>(x, W_lin, b_lin, coef, states,
                                             D, film, out);
}

// Round 2
// 546.880 us; speedup vs baseline: 1.1191x; 1.1191x over previous
//
#include <hip/hip_runtime.h>
#include <hip/hip_bf16.h>
#include <math.h>

#define B_ 16
#define L_ 32768
#define H_ 64
#define N_ 16
#define DM_ 32
#define T_ 128
#define C_ 256   /* L_/T_ */
#define TS_ 16   /* subtile rows */

typedef __attribute__((ext_vector_type(8))) short short8;
typedef __attribute__((ext_vector_type(4))) float floatx4;

// gelu matching jax.nn.gelu(approximate=True)
__device__ __forceinline__ float fast_gelu(float v) {
    float z = fmaf(0.044715f * v, v * v, v) * 0.7978845608028654f;
#if __has_builtin(__builtin_amdgcn_exp2f) && __has_builtin(__builtin_amdgcn_rcpf)
    float e = __builtin_amdgcn_exp2f(z * 2.8853900817779268f);
    float t = 1.0f - 2.0f * __builtin_amdgcn_rcpf(e + 1.0f);
#else
    float t = tanhf(z);
#endif
    return 0.5f * v * (1.0f + t);
}

__device__ __forceinline__ unsigned short bf16_rne(float f) {
    unsigned u = __float_as_uint(f);
    return (unsigned short)((u + 0x7FFFu + ((u >> 16) & 1u)) >> 16);
}
__device__ __forceinline__ float bf16_tof(unsigned short h) {
    return __uint_as_float(((unsigned)h) << 16);
}
// split 8 floats into bf16 hi + bf16 lo fragments (packed)
__device__ __forceinline__ void cvt8(const float* f, short8* hi, short8* lo) {
    union { unsigned u[4]; short8 s; } Hh, Ll;
    #pragma unroll
    for (int jp = 0; jp < 4; ++jp) {
        unsigned short h0 = bf16_rne(f[2*jp]), h1 = bf16_rne(f[2*jp+1]);
        Hh.u[jp] = (unsigned)h0 | ((unsigned)h1 << 16);
        float l0 = f[2*jp]   - bf16_tof(h0);
        float l1 = f[2*jp+1] - bf16_tof(h1);
        Ll.u[jp] = (unsigned)bf16_rne(l0) | ((unsigned)bf16_rne(l1) << 16);
    }
    *hi = Hh.s; *lo = Ll.s;
}

// ---------------- kernel 0a: cond MLP + FiLM params ----------------
__global__ void cond_film_kernel(const float* __restrict__ cp,
    const float* __restrict__ W0, const float* __restrict__ b0,
    const float* __restrict__ W1, const float* __restrict__ b1,
    const float* __restrict__ W2, const float* __restrict__ b2,
    const float* __restrict__ Wf, const float* __restrict__ bf,
    float* __restrict__ film) {
    __shared__ float ca[B_][DM_];
    __shared__ float cb[B_][DM_];
    int tid = threadIdx.x;            // 512 threads = 16 b * 32 j
    int b = tid >> 5, j = tid & 31;
    float acc = fmaf(cp[b*2+0], W0[j], fmaf(cp[b*2+1], W0[DM_+j], b0[j]));
    ca[b][j] = fast_gelu(acc);
    __syncthreads();
    acc = b1[j];
    #pragma unroll
    for (int i = 0; i < DM_; ++i) acc = fmaf(ca[b][i], W1[i*DM_+j], acc);
    cb[b][j] = fast_gelu(acc);
    __syncthreads();
    acc = b2[j];
    #pragma unroll
    for (int i = 0; i < DM_; ++i) acc = fmaf(cb[b][i], W2[i*DM_+j], acc);
    float c2 = fast_gelu(acc);
    __syncthreads();
    ca[b][j] = c2;
    __syncthreads();
    #pragma unroll
    for (int t = 0; t < 4; ++t) {
        int k = j + DM_*t;            // 0..127
        float a = bf[k];
        #pragma unroll
        for (int i = 0; i < DM_; ++i) a = fmaf(ca[b][i], Wf[i*2*H_+k], a);
        film[b*2*H_ + k] = a;         // [0:64)=gamma, [64:128)=beta
    }
}

// ---------------- kernel 0b: SSM coefficients ----------------
// coef layout: coef[(n*6+f)*H_ + h], f = {wr, wi, wTr, wTi, 2cr, 2ci}
__global__ void coef_kernel(const float* __restrict__ log_dt,
    const float* __restrict__ A_re, const float* __restrict__ A_im,
    const float* __restrict__ C_re, const float* __restrict__ C_im,
    float* __restrict__ coef) {
    int g = blockIdx.x * blockDim.x + threadIdx.x;   // 1024
    if (g >= H_*N_) return;
    int h = g >> 4, n = g & 15;
    float dt = expf(log_dt[h]);
    float Ar = A_re[h*N_+n], Ai = A_im[h*N_+n];
    float ar = dt*Ar, ai = dt*Ai;
    float er = expf(ar);
    float wr = er * cosf(ai), wi = er * sinf(ai);
    float eT = expf((float)T_ * ar);
    float aT = (float)T_ * ai;
    float wTr = eT * cosf(aT), wTi = eT * sinf(aT);
    float d  = Ar*Ar + Ai*Ai;
    float nr = wr - 1.0f, ni = wi;
    float qr = (nr*Ar + ni*Ai) / d;
    float qi = (ni*Ar - nr*Ai) / d;
    float Cr = C_re[h*N_+n], Ci = C_im[h*N_+n];
    float cr = 2.0f * (Cr*qr - Ci*qi);   // fold the 2*Re() factor in
    float ci = 2.0f * (Cr*qi + Ci*qr);
    coef[(n*6+0)*H_+h] = wr;
    coef[(n*6+1)*H_+h] = wi;
    coef[(n*6+2)*H_+h] = wTr;
    coef[(n*6+3)*H_+h] = wTi;
    coef[(n*6+4)*H_+h] = cr;
    coef[(n*6+5)*H_+h] = ci;
}

// ---------------- phase 2: cross-chunk prefix combine (prefetch depth 8) ----
// states layout: states[(((b*C_ + c)*N_ + n)*H_ + h)*2 + {0,1}]
__global__ void chunk_scan_kernel(float* __restrict__ states,
                                  const float* __restrict__ coef) {
    int t = blockIdx.x * blockDim.x + threadIdx.x;   // 16384 = B*N*H
    int h = t & 63, n = (t >> 6) & 15, b = t >> 10;
    float wTr = coef[(n*6+2)*H_+h], wTi = coef[(n*6+3)*H_+h];
    float2* sp = (float2*)states + ((size_t)b*C_)*N_*H_ + (size_t)n*H_ + h;
    const int stride = N_*H_;        // float2 units per chunk
    float car = 0.f, cai = 0.f;
    float2 buf[8];
    #pragma unroll
    for (int i = 0; i < 8; ++i) buf[i] = sp[(size_t)i*stride];
    for (int cg = 0; cg < C_; cg += 8) {
        float2 nb[8];
        #pragma unroll
        for (int i = 0; i < 8; ++i)
            nb[i] = (cg + 8 + i < C_) ? sp[(size_t)(cg+8+i)*stride]
                                      : make_float2(0.f, 0.f);
        #pragma unroll
        for (int i = 0; i < 8; ++i) {
            float2 v = buf[i];
            sp[(size_t)(cg+i)*stride] = make_float2(car, cai);
            float nr2 = fmaf(wTr, car, fmaf(-wTi, cai, v.x));
            float ni2 = fmaf(wTr, cai, fmaf( wTi, car, v.y));
            car = nr2; cai = ni2;
            buf[i] = nb[i];
        }
    }
}

// ---------------- phases 1 & 3: MFMA GEMM + diagonal scan ----------------
// PHASE 1: zero-init states, write end-of-chunk local states.
// PHASE 3: init from prefix states, write final output (FiLM+gelu+gate fused).
// One wave per chunk, 4 waves per block. u = gelu(x@W+b) via split-bf16 MFMA:
//   u ~= x_hi@W_hi + x_lo@W_hi + x_hi@W_lo   (error ~2^-17)
template<int PHASE>
__global__ __launch_bounds__(256, 3)
void gemm_scan_kernel(const float* __restrict__ x,
                      const float* __restrict__ W_lin, const float* __restrict__ b_lin,
                      const float* __restrict__ coef, float* __restrict__ states,
                      const float* __restrict__ D, const float* __restrict__ film,
                      float* __restrict__ out) {
    // W fragment table: frag f = (t*2+kt)*4+nt (t=0 hi, t=1 lo), 16 frags * 64 lanes * 16B
    __shared__ __align__(16) unsigned short Wf[16*64*8];     // 16 KB
    __shared__ float uld[4][TS_*65];                          // 4 * 4.16 KB
    const int lane = threadIdx.x & 63;
    const int wv   = threadIdx.x >> 6;
    const int q    = blockIdx.x*4 + wv;        // chunk id 0..4095
    const int b    = q >> 8;
    const int c    = q & 255;
    const int m    = lane & 15;
    const int quad = lane >> 4;

    // ---- build W fragments in LDS (each wave writes full table; identical values,
    //      so no barrier needed — per-wave DS ordering covers own writes) ----
    for (int kt = 0; kt < 2; ++kt)
        for (int nt = 0; nt < 4; ++nt) {
            float f[8];
            #pragma unroll
            for (int j = 0; j < 8; ++j)
                f[j] = W_lin[(kt*32 + quad*8 + j)*H_ + nt*16 + m];
            short8 hi, lo;
            cvt8(f, &hi, &lo);
            ((short8*)Wf)[(kt*4 + nt)*64 + lane]     = hi;   // t=0
            ((short8*)Wf)[((2+kt)*4 + nt)*64 + lane] = lo;   // t=1
        }

    // ---- scan coefficients / state init ----
    float wr[N_], wi[N_], sr[N_], si[N_];
    float cr[N_], ci[N_];
    float g_ = 0.f, be_ = 0.f, Dh = 0.f;
    #pragma unroll
    for (int n = 0; n < N_; ++n) {
        wr[n] = coef[(n*6+0)*H_ + lane];
        wi[n] = coef[(n*6+1)*H_ + lane];
    }
    if (PHASE == 1) {
        #pragma unroll
        for (int n = 0; n < N_; ++n) { sr[n] = 0.f; si[n] = 0.f; }
    } else {
        #pragma unroll
        for (int n = 0; n < N_; ++n) {
            cr[n] = coef[(n*6+4)*H_ + lane];
            ci[n] = coef[(n*6+5)*H_ + lane];
            size_t idx = (((size_t)q*N_ + n)*H_ + lane)*2;
            sr[n] = states[idx]; si[n] = states[idx+1];
        }
        g_  = film[b*2*H_ + lane];
        be_ = film[b*2*H_ + H_ + lane];
        Dh  = D[lane];
    }
    float blv[4];
    #pragma unroll
    for (int nt = 0; nt < 4; ++nt) blv[nt] = b_lin[nt*16 + m];

    const float* xp = x + ((size_t)b*L_ + (size_t)c*T_)*H_;
    float* op = out + ((size_t)b*L_ + (size_t)c*T_)*H_;
    float* myu = uld[wv];

    for (int s = 0; s < T_/TS_; ++s) {
        const float* xs = xp + s*TS_*H_;
        // A fragments straight from global: A[m=lane&15][k=kt*32+quad*8+j]
        short8 ah[2], al[2];
        #pragma unroll
        for (int kt = 0; kt < 2; ++kt) {
            const float* src = xs + m*H_ + kt*32 + quad*8;
            float4 v0 = *(const float4*)(src);
            float4 v1 = *(const float4*)(src + 4);
            float f[8] = {v0.x, v0.y, v0.z, v0.w, v1.x, v1.y, v1.z, v1.w};
            cvt8(f, &ah[kt], &al[kt]);
        }
        // MFMA + epilogue: gelu, transpose u through LDS (row stride 65)
        #pragma unroll
        for (int nt = 0; nt < 4; ++nt) {
            floatx4 acc = {0.f, 0.f, 0.f, 0.f};
            #pragma unroll
            for (int kt = 0; kt < 2; ++kt) {
                short8 bh = ((short8*)Wf)[(kt*4 + nt)*64 + lane];
                short8 bl = ((short8*)Wf)[((2+kt)*4 + nt)*64 + lane];
                acc = __builtin_amdgcn_mfma_f32_16x16x32_bf16(ah[kt], bh, acc, 0, 0, 0);
                acc = __builtin_amdgcn_mfma_f32_16x16x32_bf16(al[kt], bh, acc, 0, 0, 0);
                acc = __builtin_amdgcn_mfma_f32_16x16x32_bf16(ah[kt], bl, acc, 0, 0, 0);
            }
            // C layout: col = nt*16 + (lane&15), row = quad*4 + reg
            #pragma unroll
            for (int r = 0; r < 4; ++r) {
                int row = quad*4 + r;
                float uv = fast_gelu(acc[r] + blv[nt]);
                myu[row*65 + nt*16 + m] = uv;
            }
        }
        // scan TS_ rows (lane = h); per-wave DS ordering makes writes visible
        for (int l = 0; l < TS_; ++l) {
            float uv = myu[l*65 + lane];
            if (PHASE == 1) {
                #pragma unroll
                for (int n = 0; n < N_; ++n) {
                    float nr = fmaf(wr[n], sr[n], fmaf(-wi[n], si[n], uv));
                    float ni = fmaf(wr[n], si[n], wi[n]*sr[n]);
                    sr[n] = nr; si[n] = ni;
                }
            } else {
                float xg = xs[l*H_ + lane];
                float y0 = 0.f, y1 = 0.f;
                #pragma unroll
                for (int n = 0; n < N_; ++n) {
                    float nr = fmaf(wr[n], sr[n], fmaf(-wi[n], si[n], uv));
                    float ni = fmaf(wr[n], si[n], wi[n]*sr[n]);
                    sr[n] = nr; si[n] = ni;
                    y0 = fmaf(cr[n], nr, y0);
                    y1 = fmaf(ci[n], ni, y1);
                }
                float y  = fmaf(Dh, uv, y0 - y1);     // conv + D*u
                float yg = fast_gelu(fmaf(y, g_, be_)); // FiLM + gelu
                op[(s*TS_ + l)*H_ + lane] = xg * yg;  // side-chain gate
            }
        }
    }
    if (PHASE == 1) {
        #pragma unroll
        for (int n = 0; n < N_; ++n) {
            size_t idx = (((size_t)q*N_ + n)*H_ + lane)*2;
            states[idx]   = sr[n];
            states[idx+1] = si[n];
        }
    }
}

extern "C" void kernel_launch(void* const* d_in, const int* in_sizes, int n_in,
                              void* d_out, int out_size, void* d_ws, size_t ws_size,
                              hipStream_t stream) {
    const float* x     = (const float*)d_in[0];
    const float* cp    = (const float*)d_in[1];
    const float* W0    = (const float*)d_in[2];
    const float* b0    = (const float*)d_in[3];
    const float* W1    = (const float*)d_in[4];
    const float* b1    = (const float*)d_in[5];
    const float* W2    = (const float*)d_in[6];
    const float* b2    = (const float*)d_in[7];
    const float* W_lin = (const float*)d_in[8];
    const float* b_lin = (const float*)d_in[9];
    const float* log_dt= (const float*)d_in[10];
    const float* A_re  = (const float*)d_in[11];
    const float* A_im  = (const float*)d_in[12];
    const float* C_re  = (const float*)d_in[13];
    const float* C_im  = (const float*)d_in[14];
    const float* D     = (const float*)d_in[15];
    const float* W_f   = (const float*)d_in[16];
    const float* b_f   = (const float*)d_in[17];
    float* out = (float*)d_out;

    float* film   = (float*)d_ws;                  // B*2H       = 2048 floats
    float* coef   = film + B_*2*H_;                // 6*H*N      = 6144 floats
    float* states = coef + 6*H_*N_;                // B*C*N*H*2  = 8.4M floats

    cond_film_kernel<<<1, 512, 0, stream>>>(cp, W0, b0, W1, b1, W2, b2,
                                            W_f, b_f, film);
    coef_kernel<<<4, 256, 0, stream>>>(log_dt, A_re, A_im, C_re, C_im, coef);
    gemm_scan_kernel<1><<<(B_*C_)/4, 256, 0, stream>>>(x, W_lin, b_lin, coef,
                                                       states, nullptr, nullptr, nullptr);
    chunk_scan_kernel<<<(B_*N_*H_)/256, 256, 0, stream>>>(states, coef);
    gemm_scan_kernel<3><<<(B_*C_)/4, 256, 0, stream>>>(x, W_lin, b_lin, coef,
                                                       states, D, film, out);
}